// Round 9
// baseline (123.322 us; speedup 1.0000x reference)
//
#include <hip/hip_runtime.h>

#define BATCH  1024
#define IN_SZ  2048
#define OUT_SZ 2048
#define E_N    131072

#define NT     256
#define NSEG   2                 // fill cursor segments (contention split)
#define SEG_D  64                // ELL depth per segment (Poisson(32) tail-safe)
#define K_MAX  (NSEG * SEG_D)    // 128
#define CPAD   16                // cursor stride in ints = 64 B (one per cacheline)
#define ZERO_BLKS 16

__device__ __forceinline__ unsigned int bf16_rne(float f) {
    unsigned int u = __float_as_uint(f);
    return (u + 0x7FFFu + ((u >> 16) & 1u)) >> 16;   // round-to-nearest-even
}

// ---------- prep1: transpose x[1024][2048] f32 -> xt[2048][1024] bf16 ----------
// 512 blocks = 32x16 tiles of 64x64. Blocks 0..15 also zero the cursor region
// (fill runs in the NEXT kernel, so cross-block ordering is guaranteed).
__global__ __launch_bounds__(NT) void prep1_kernel(const float* __restrict__ x,
                                                   unsigned short* __restrict__ xt,
                                                   int* __restrict__ cursor) {
    __shared__ float lds[64][65];   // +1 pitch: conflict-free column reads
    const int tid = threadIdx.x;
    const int b   = blockIdx.x;

    if (b < ZERO_BLKS) {            // 65536 ints / 16 blocks = 1024 int4 each
        int4* c4 = (int4*)cursor;
        #pragma unroll
        for (int k = 0; k < 4; ++k)
            c4[b * 1024 + k * NT + tid] = make_int4(0, 0, 0, 0);
    }

    const int c0 = (b & 31) * 64;   // col tile
    const int r0 = (b >> 5) * 64;   // row tile
    #pragma unroll
    for (int k = 0; k < 16; ++k) {  // coalesced 64-float row segments
        const int idx = k * NT + tid;
        const int r = idx >> 6, cl = idx & 63;
        lds[r][cl] = x[(size_t)(r0 + r) * IN_SZ + c0 + cl];
    }
    __syncthreads();
    #pragma unroll
    for (int k = 0; k < 8; ++k) {   // write xt rows: 32 consecutive u32 per col
        const int idx = k * NT + tid;
        const int cl = idx >> 5;
        const int rp = (idx & 31) * 2;
        const unsigned int v = bf16_rne(lds[rp][cl]) | (bf16_rne(lds[rp + 1][cl]) << 16);
        *(unsigned int*)&xt[(size_t)(c0 + cl) * BATCH + r0 + rp] = v;
    }
}

// ---------- prep2: fill column-contiguous ELL via padded atomic cursors ----------
// packed entry = bf16(w)<<16 | i  (i < 2048 fits 11 bits)
__global__ void fill_kernel(const int4* __restrict__ iidx4, const int4* __restrict__ oidx4,
                            const float4* __restrict__ w4,
                            int* __restrict__ cursor, unsigned int* __restrict__ ell) {
    const int t = blockIdx.x * NT + threadIdx.x;   // grid 128x256 = E_N/4 quads
    const int4   ii = iidx4[t];
    const int4   oo = oidx4[t];
    const float4 ww = w4[t];
    const int ebase = t * 4;
    #pragma unroll
    for (int j = 0; j < 4; ++j) {
        const int i = (&ii.x)[j];
        const int o = (&oo.x)[j];
        const unsigned int packed = (bf16_rne((&ww.x)[j]) << 16) | (unsigned int)i;
        const int s = (ebase + j) >> 16;           // segment 0/1
        const int pos = atomicAdd(&cursor[(s * OUT_SZ + o) * CPAD], 1);
        if (pos < SEG_D)   // statistically impossible; guards OOB
            ell[(size_t)o * K_MAX + s * SEG_D + pos] = packed;
    }
}

// ---------- spmm2: batch-on-lanes; entries preloaded + __shfl broadcast ----------
// Wave = 1 column x 256 rows (4 rows/lane). Entry slots live in 2 per-lane
// registers (1 coalesced load per segment); in-loop broadcast is ds_bpermute
// (no vmcnt drain). Only vmem op in the loop: the coalesced 512B xv gather,
// independent across k -> multiple in flight.
__global__ __launch_bounds__(NT) void spmm2_kernel(const unsigned short* __restrict__ xt,
                                                   const unsigned int* __restrict__ ell,
                                                   const int* __restrict__ cursor,
                                                   float* __restrict__ out) {
    __shared__ float tile[256][9];   // rows x 8 cols, pitch 9 (9.2 KB)
    const int tid  = threadIdx.x;
    const int w    = tid >> 6;
    const int lane = tid & 63;
    const int c0   = blockIdx.x * 8;          // 8 columns per block (2 per wave)
    const int r0   = blockIdx.y * 256;        // 256 rows per block
    const unsigned short* xtb = xt + r0 + lane * 4;   // lane's 4-row slice base

#define PROC(e)                                                         \
    {                                                                   \
        const float wv = __uint_as_float((e) & 0xFFFF0000u);            \
        const uint2 xv = *(const uint2*)(xtb + (((e) & 0x7FFu) << 10)); \
        a0 = fmaf(wv, __uint_as_float(xv.x << 16),         a0);         \
        a1 = fmaf(wv, __uint_as_float(xv.x & 0xFFFF0000u), a1);         \
        a2 = fmaf(wv, __uint_as_float(xv.y << 16),         a2);         \
        a3 = fmaf(wv, __uint_as_float(xv.y & 0xFFFF0000u), a3);         \
    }

    #pragma unroll
    for (int p = 0; p < 2; ++p) {
        const int cs = c0 + w * 2 + p;
        const unsigned int* ep = ell + (size_t)cs * K_MAX;
        // Preload both segments' slot tables into registers (lane k = slot k).
        const unsigned int er0 = ep[lane];
        const unsigned int er1 = ep[SEG_D + lane];
        int cnt0 = cursor[(0 * OUT_SZ + cs) * CPAD];
        int cnt1 = cursor[(1 * OUT_SZ + cs) * CPAD];
        cnt0 = cnt0 < SEG_D ? cnt0 : SEG_D;   // uniform at runtime
        cnt1 = cnt1 < SEG_D ? cnt1 : SEG_D;

        float a0 = 0.f, a1 = 0.f, a2 = 0.f, a3 = 0.f;
        #pragma unroll 4
        for (int k = 0; k < cnt0; ++k) {
            const unsigned int e = (unsigned int)__shfl((int)er0, k);
            PROC(e);
        }
        #pragma unroll 4
        for (int k = 0; k < cnt1; ++k) {
            const unsigned int e = (unsigned int)__shfl((int)er1, k);
            PROC(e);
        }

        const int cl = w * 2 + p;
        tile[lane * 4 + 0][cl] = a0;
        tile[lane * 4 + 1][cl] = a1;
        tile[lane * 4 + 2][cl] = a2;
        tile[lane * 4 + 3][cl] = a3;
    }
#undef PROC
    __syncthreads();

    // Epilogue: thread t stores row r0+t, cols c0..c0+7 (two dwordx4 = 32 B)
    float* op = out + (size_t)(r0 + tid) * OUT_SZ + c0;
    *(float4*)op       = make_float4(tile[tid][0], tile[tid][1], tile[tid][2], tile[tid][3]);
    *(float4*)(op + 4) = make_float4(tile[tid][4], tile[tid][5], tile[tid][6], tile[tid][7]);
}

// ---------- fallback (slow but correct) if ws is too small ----------
__global__ __launch_bounds__(NT) void sparse_row_kernel(
    const float* __restrict__ x, const float* __restrict__ w,
    const int* __restrict__ iidx, const int* __restrict__ oidx,
    float* __restrict__ out) {
    __shared__ float xs[IN_SZ];
    __shared__ float acc[OUT_SZ];
    const int b = blockIdx.x, tid = threadIdx.x;
    const float4* xrow = (const float4*)(x + (size_t)b * IN_SZ);
    float4* xs4 = (float4*)xs;
    for (int t = tid; t < IN_SZ / 4; t += NT) xs4[t] = xrow[t];
    float4* acc4 = (float4*)acc;
    const float4 z = make_float4(0.f, 0.f, 0.f, 0.f);
    for (int t = tid; t < OUT_SZ / 4; t += NT) acc4[t] = z;
    __syncthreads();
    for (int e = tid; e < E_N; e += NT)
        atomicAdd(&acc[oidx[e]], w[e] * xs[iidx[e]]);
    __syncthreads();
    float4* orow = (float4*)(out + (size_t)b * OUT_SZ);
    for (int t = tid; t < OUT_SZ / 4; t += NT) orow[t] = acc4[t];
}

extern "C" void kernel_launch(void* const* d_in, const int* in_sizes, int n_in,
                              void* d_out, int out_size, void* d_ws, size_t ws_size,
                              hipStream_t stream) {
    const float* x    = (const float*)d_in[0];   // [1024, 2048] fp32
    const float* wts  = (const float*)d_in[1];   // [131072] fp32
    const int*   iidx = (const int*)d_in[2];     // [131072] int32
    const int*   oidx = (const int*)d_in[3];     // [131072] int32
    float* out = (float*)d_out;                  // [1024, 2048] fp32
    (void)in_sizes; (void)n_in; (void)out_size;

    // ws: cursor[NSEG*2048*CPAD] ints (256 KB) | ell[2048][K_MAX] u32 (1 MB)
    //     | xt[2048][1024] bf16 (4 MB)
    const size_t cursor_bytes = (size_t)NSEG * OUT_SZ * CPAD * sizeof(int);
    const size_t ell_bytes    = (size_t)OUT_SZ * K_MAX * sizeof(unsigned int);
    const size_t xt_bytes     = (size_t)IN_SZ * BATCH * sizeof(unsigned short);
    if (ws_size < cursor_bytes + ell_bytes + xt_bytes) {
        sparse_row_kernel<<<BATCH, NT, 0, stream>>>(x, wts, iidx, oidx, out);
        return;
    }

    int* cursor = (int*)d_ws;
    unsigned int*   ell = (unsigned int*)((char*)d_ws + cursor_bytes);
    unsigned short* xt  = (unsigned short*)((char*)d_ws + cursor_bytes + ell_bytes);

    prep1_kernel<<<512, NT, 0, stream>>>(x, xt, cursor);             // tx + cursor zero
    fill_kernel<<<E_N / 4 / NT, NT, 0, stream>>>((const int4*)iidx, (const int4*)oidx,
                                                 (const float4*)wts, cursor, ell);
    dim3 grid(OUT_SZ / 8, BATCH / 256);                              // 256 x 4 = 1024
    spmm2_kernel<<<grid, NT, 0, stream>>>(xt, ell, cursor, out);
}

// Round 10
// 99.051 us; speedup vs baseline: 1.2450x; 1.2450x over previous
//
#include <hip/hip_runtime.h>

#define BATCH  1024
#define IN_SZ  2048
#define OUT_SZ 2048
#define E_N    131072

#define NSEG   2                 // fill cursor segments (contention split)
#define SEG_D  64                // ELL depth per segment (Poisson(32) tail-safe)
#define K_MAX  (NSEG * SEG_D)    // 128
#define CPAD   16                // cursor stride in ints = 64 B (one per cacheline)
#define ZERO_BLKS 16
#define NT     256
#define NTW    512               // spmm3 block: 8 waves

__device__ __forceinline__ unsigned int bf16_rne(float f) {
    unsigned int u = __float_as_uint(f);
    return (u + 0x7FFFu + ((u >> 16) & 1u)) >> 16;   // round-to-nearest-even
}

// ---------- prep1: transpose x -> xt[2048][1024] bf16; zero cursors + ELL ----------
__global__ __launch_bounds__(NT) void prep1_kernel(const float* __restrict__ x,
                                                   unsigned short* __restrict__ xt,
                                                   int* __restrict__ cursor,
                                                   int4* __restrict__ ell4) {
    __shared__ float lds[64][65];   // +1 pitch: conflict-free column reads
    const int tid = threadIdx.x;
    const int b   = blockIdx.x;

    if (b < ZERO_BLKS) {            // zero 65536 cursor ints: 1024 int4/block
        int4* c4 = (int4*)cursor;
        #pragma unroll
        for (int k = 0; k < 4; ++k)
            c4[b * 1024 + k * NT + tid] = make_int4(0, 0, 0, 0);
    }
    // zero ELL (1 MB = 65536 int4): 128 int4 per block
    if (tid < 128) ell4[b * 128 + tid] = make_int4(0, 0, 0, 0);

    const int c0 = (b & 31) * 64;   // col tile
    const int r0 = (b >> 5) * 64;   // row tile
    #pragma unroll
    for (int k = 0; k < 16; ++k) {  // coalesced 64-float row segments
        const int idx = k * NT + tid;
        const int r = idx >> 6, cl = idx & 63;
        lds[r][cl] = x[(size_t)(r0 + r) * IN_SZ + c0 + cl];
    }
    __syncthreads();
    #pragma unroll
    for (int k = 0; k < 8; ++k) {   // write xt rows: 32 consecutive u32 per col
        const int idx = k * NT + tid;
        const int cl = idx >> 5;
        const int rp = (idx & 31) * 2;
        const unsigned int v = bf16_rne(lds[rp][cl]) | (bf16_rne(lds[rp + 1][cl]) << 16);
        *(unsigned int*)&xt[(size_t)(c0 + cl) * BATCH + r0 + rp] = v;
    }
}

// ---------- prep2: fill column-contiguous ELL via padded atomic cursors ----------
// packed entry = bf16(w)<<16 | i  (i < 2048 fits 11 bits)
__global__ void fill_kernel(const int4* __restrict__ iidx4, const int4* __restrict__ oidx4,
                            const float4* __restrict__ w4,
                            int* __restrict__ cursor, unsigned int* __restrict__ ell) {
    const int t = blockIdx.x * NT + threadIdx.x;   // grid 128x256 = E_N/4 quads
    const int4   ii = iidx4[t];
    const int4   oo = oidx4[t];
    const float4 ww = w4[t];
    const int ebase = t * 4;
    #pragma unroll
    for (int j = 0; j < 4; ++j) {
        const int i = (&ii.x)[j];
        const int o = (&oo.x)[j];
        const unsigned int packed = (bf16_rne((&ww.x)[j]) << 16) | (unsigned int)i;
        const int s = (ebase + j) >> 16;           // segment 0/1
        const int pos = atomicAdd(&cursor[(s * OUT_SZ + o) * CPAD], 1);
        if (pos < SEG_D)   // statistically impossible; guards OOB
            ell[(size_t)o * K_MAX + s * SEG_D + pos] = packed;
    }
}

// ---------- spmm3 helper: one ELL segment, 16-entry scalar-chunk pipeline ----------
// base: segment's 64-slot table (zero-padded). Chunk g's entry vector is loaded
// one chunk ahead; in-chunk broadcast is readlane with LITERAL index -> SGPR ->
// scalar address math. The 16 gathers per chunk are independent (deep MLP).
__device__ __forceinline__ void seg_accum(const unsigned int* __restrict__ base, int cnt,
                                          const unsigned short* __restrict__ xtb,
                                          int lane, float& a0, float& a1, float& a2, float& a3) {
    const int nch = (cnt + 15) >> 4;
    if (nch <= 0) return;
    unsigned int ev = base[lane & 15];
    for (int g = 0; g < nch; ++g) {
        const int gn = (g + 1 < nch) ? (g + 1) : g;
        const unsigned int evn = base[gn * 16 + (lane & 15)];   // prefetch next chunk
        #pragma unroll
        for (int j = 0; j < 16; ++j) {
            const unsigned int e = (unsigned int)__builtin_amdgcn_readlane((int)ev, j);
            const float wv = __uint_as_float(e & 0xFFFF0000u);
            const uint2 xv = *(const uint2*)(xtb + ((e & 0x7FFu) << 10));  // i*1024 shorts
            a0 = fmaf(wv, __uint_as_float(xv.x << 16),         a0);
            a1 = fmaf(wv, __uint_as_float(xv.x & 0xFFFF0000u), a1);
            a2 = fmaf(wv, __uint_as_float(xv.y << 16),         a2);
            a3 = fmaf(wv, __uint_as_float(xv.y & 0xFFFF0000u), a3);
        }
        ev = evn;
    }
}

// ---------- spmm3: 8 waves/block; wave = 1 column x 256 rows (4 rows/lane) ----------
__global__ __launch_bounds__(NTW) void spmm3_kernel(const unsigned short* __restrict__ xt,
                                                    const unsigned int* __restrict__ ell,
                                                    const int* __restrict__ cursor,
                                                    float* __restrict__ out) {
    __shared__ float tile[256][9];   // rows x 8 cols, pitch 9
    const int tid  = threadIdx.x;
    const int w    = tid >> 6;
    const int lane = tid & 63;
    const int c0   = blockIdx.x * 8;
    const int r0   = blockIdx.y * 256;

    const int cs = __builtin_amdgcn_readfirstlane(c0 + w);   // wave's column (scalar)
    int cnt0 = cursor[(0 * OUT_SZ + cs) * CPAD];
    int cnt1 = cursor[(1 * OUT_SZ + cs) * CPAD];
    cnt0 = cnt0 < SEG_D ? cnt0 : SEG_D;
    cnt1 = cnt1 < SEG_D ? cnt1 : SEG_D;
    const unsigned int* ep = ell + (size_t)cs * K_MAX;
    const unsigned short* xtb = xt + r0 + lane * 4;          // lane's 4-row slice

    float a0 = 0.f, a1 = 0.f, a2 = 0.f, a3 = 0.f;
    seg_accum(ep,         cnt0, xtb, lane, a0, a1, a2, a3);
    seg_accum(ep + SEG_D, cnt1, xtb, lane, a0, a1, a2, a3);

    tile[lane * 4 + 0][w] = a0;
    tile[lane * 4 + 1][w] = a1;
    tile[lane * 4 + 2][w] = a2;
    tile[lane * 4 + 3][w] = a3;
    __syncthreads();

    // Epilogue: thread t -> row t>>1, col-half t&1 (float4 = 16 B; 32 B/row pair)
    const int row = tid >> 1, half = (tid & 1) * 4;
    float* op = out + (size_t)(r0 + row) * OUT_SZ + c0 + half;
    *(float4*)op = make_float4(tile[row][half + 0], tile[row][half + 1],
                               tile[row][half + 2], tile[row][half + 3]);
}

// ---------- fallback (slow but correct) if ws is too small ----------
__global__ __launch_bounds__(NT) void sparse_row_kernel(
    const float* __restrict__ x, const float* __restrict__ w,
    const int* __restrict__ iidx, const int* __restrict__ oidx,
    float* __restrict__ out) {
    __shared__ float xs[IN_SZ];
    __shared__ float acc[OUT_SZ];
    const int b = blockIdx.x, tid = threadIdx.x;
    const float4* xrow = (const float4*)(x + (size_t)b * IN_SZ);
    float4* xs4 = (float4*)xs;
    for (int t = tid; t < IN_SZ / 4; t += NT) xs4[t] = xrow[t];
    float4* acc4 = (float4*)acc;
    const float4 z = make_float4(0.f, 0.f, 0.f, 0.f);
    for (int t = tid; t < OUT_SZ / 4; t += NT) acc4[t] = z;
    __syncthreads();
    for (int e = tid; e < E_N; e += NT)
        atomicAdd(&acc[oidx[e]], w[e] * xs[iidx[e]]);
    __syncthreads();
    float4* orow = (float4*)(out + (size_t)b * OUT_SZ);
    for (int t = tid; t < OUT_SZ / 4; t += NT) orow[t] = acc4[t];
}

extern "C" void kernel_launch(void* const* d_in, const int* in_sizes, int n_in,
                              void* d_out, int out_size, void* d_ws, size_t ws_size,
                              hipStream_t stream) {
    const float* x    = (const float*)d_in[0];   // [1024, 2048] fp32
    const float* wts  = (const float*)d_in[1];   // [131072] fp32
    const int*   iidx = (const int*)d_in[2];     // [131072] int32
    const int*   oidx = (const int*)d_in[3];     // [131072] int32
    float* out = (float*)d_out;                  // [1024, 2048] fp32
    (void)in_sizes; (void)n_in; (void)out_size;

    // ws: cursor[NSEG*2048*CPAD] ints (256 KB) | ell[2048][K_MAX] u32 (1 MB)
    //     | xt[2048][1024] bf16 (4 MB)
    const size_t cursor_bytes = (size_t)NSEG * OUT_SZ * CPAD * sizeof(int);
    const size_t ell_bytes    = (size_t)OUT_SZ * K_MAX * sizeof(unsigned int);
    const size_t xt_bytes     = (size_t)IN_SZ * BATCH * sizeof(unsigned short);
    if (ws_size < cursor_bytes + ell_bytes + xt_bytes) {
        sparse_row_kernel<<<BATCH, NT, 0, stream>>>(x, wts, iidx, oidx, out);
        return;
    }

    int* cursor = (int*)d_ws;
    unsigned int*   ell = (unsigned int*)((char*)d_ws + cursor_bytes);
    unsigned short* xt  = (unsigned short*)((char*)d_ws + cursor_bytes + ell_bytes);

    prep1_kernel<<<512, NT, 0, stream>>>(x, xt, cursor, (int4*)ell);
    fill_kernel<<<E_N / 4 / NT, NT, 0, stream>>>((const int4*)iidx, (const int4*)oidx,
                                                 (const float4*)wts, cursor, ell);
    dim3 grid(OUT_SZ / 8, BATCH / 256);          // 256 x 4 = 1024 blocks of 512
    spmm3_kernel<<<grid, NTW, 0, stream>>>(xt, ell, cursor, out);
}